// Round 7
// baseline (72.548 us; speedup 1.0000x reference)
//
#include <hip/hip_runtime.h>

#define BATCH 262144
#define BLOCK 256
// 2 batch elements per thread -> 512 elements per block
#define GRID  (BATCH / (BLOCK * 2))

typedef float v2 __attribute__((ext_vector_type(2)));

struct c2f { float re, im; };

__device__ __forceinline__ c2f cmul(c2f a, c2f b){
    return { a.re*b.re - a.im*b.im, a.re*b.im + a.im*b.re };
}
__device__ __forceinline__ c2f cmulc(c2f a, c2f b){  // a * conj(b)
    return { a.re*b.re + a.im*b.im, a.im*b.re - a.re*b.im };
}
// SU(2) matrices stored as (alpha, beta): M = [[a, b], [-conj(b), conj(a)]]
__device__ __forceinline__ void su2mul(c2f a1, c2f b1, c2f a2, c2f b2, c2f& ao, c2f& bo){
    c2f t1 = cmul(a1, a2), t2 = cmulc(b1, b2);
    ao = { t1.re - t2.re, t1.im - t2.im };
    c2f t3 = cmul(a1, b2), t4 = cmulc(b1, a2);
    bo = { t3.re + t4.re, t3.im + t4.im };
}
// CZ diagonal sign: qubit 0 = MSB (bit 3). Pairs (0,1),(1,2),(2,3),(0,3).
// Negative states: {3,6,9,12}.
__device__ __forceinline__ int czneg(int s){
    int b0 = (s >> 3) & 1, b1 = (s >> 2) & 1, b2 = (s >> 1) & 1, b3 = s & 1;
    return (b0 & b1) ^ (b1 & b2) ^ (b2 & b3) ^ (b0 & b3);
}

__device__ __forceinline__ v2 pkfma(v2 a, v2 b, v2 c){
    return __builtin_elementwise_fma(a, b, c);   // -> v_pk_fma_f32
}

__global__ __launch_bounds__(BLOCK) void vqc_kernel(
    const float* __restrict__ x,      // (BATCH,4) f32
    const float* __restrict__ theta,  // 48 f32
    const float* __restrict__ lmbd,   // 12 f32
    float* __restrict__ out)          // (BATCH,4) f32
{
    const int tid = threadIdx.x;
    // Two elements per thread; consecutive threads load consecutive float4s
    // within each half -> both loads fully coalesced. Issued first so HBM
    // latency hides under the uniform precompute + barriers.
    const int i0 = blockIdx.x * (BLOCK * 2) + tid;
    const int i1 = i0 + BLOCK;
    const float4 xrA = ((const float4*)x)[i0];
    const float4 xrB = ((const float4*)x)[i1];

    // --- per-block precompute of batch-independent SU(2) factors ---
    __shared__ float2 sU[4][4][2];   // [param layer 0..3][qubit][alpha,beta]
    __shared__ float2 sA[3][4][2];   // A^(0)=U1*W, A^(1)=U2*W, A^(2)=W  (W=U3)
    __shared__ float2 sPsi0[16];     // CZ * (tensor U^(0)) |0>
    __shared__ float  sLs[12];       // lmbd

    if (tid < 16) {
        int l = tid >> 2, q = tid & 3;
        float t0 = 0.5f * theta[(l * 4 + q) * 3 + 0];
        float t1 = 0.5f * theta[(l * 4 + q) * 3 + 1];
        float t2 = 0.5f * theta[(l * 4 + q) * 3 + 2];
        float c0, s0, c1, s1, c2v, s2v;
        __sincosf(t0, &s0, &c0);
        __sincosf(t1, &s1, &c1);
        __sincosf(t2, &s2v, &c2v);
        // RY(t1)*RX(t0): alpha = c1 c0 + i s1 s0 ; beta = -s1 c0 - i c1 s0
        c2f aP = { c1 * c0, s1 * s0 };
        c2f bP = { -s1 * c0, -c1 * s0 };
        // RZ(t2)*P: multiply (alpha,beta) by e^{-i t2/2}
        c2f ph = { c2v, -s2v };
        c2f aU = cmul(ph, aP);
        c2f bU = cmul(ph, bP);
        sU[l][q][0] = make_float2(aU.re, aU.im);
        sU[l][q][1] = make_float2(bU.re, bU.im);
    }
    if (tid < 12) sLs[tid] = lmbd[tid];
    __syncthreads();

    if (tid < 12) {
        int k = tid >> 2, q = tid & 3;
        c2f aW = { sU[3][q][0].x, sU[3][q][0].y };
        c2f bW = { sU[3][q][1].x, sU[3][q][1].y };
        c2f aA = aW, bA = bW;
        if (k < 2) {
            c2f aN = { sU[k + 1][q][0].x, sU[k + 1][q][0].y };
            c2f bN = { sU[k + 1][q][1].x, sU[k + 1][q][1].y };
            su2mul(aN, bN, aW, bW, aA, bA);   // U^(k+1) * W
        }
        sA[k][q][0] = make_float2(aA.re, aA.im);
        sA[k][q][1] = make_float2(bA.re, bA.im);
    }
    if (tid >= 16 && tid < 32) {
        int s = tid - 16;
        c2f v = { 1.f, 0.f };
        #pragma unroll
        for (int q = 0; q < 4; ++q) {
            int bit = (s >> (3 - q)) & 1;
            // column 0 of U: bit0 -> alpha ; bit1 -> -conj(beta)
            c2f a = { sU[0][q][0].x, sU[0][q][0].y };
            c2f b2 = { sU[0][q][1].x, sU[0][q][1].y };
            c2f e = bit ? c2f{ -b2.re, b2.im } : a;
            v = cmul(v, e);
        }
        if (czneg(s)) { v.re = -v.re; v.im = -v.im; }
        sPsi0[s] = make_float2(v.re, v.im);
    }
    __syncthreads();

    // --- hoist ALL uniforms out of LDS into registers (literal indices ->
    //     promoted; main loop has ZERO ds_read / lgkmcnt waits) ---
    float2 rA[3][4][2];
    #pragma unroll
    for (int k = 0; k < 3; ++k)
        #pragma unroll
        for (int q = 0; q < 4; ++q) {
            rA[k][q][0] = sA[k][q][0];
            rA[k][q][1] = sA[k][q][1];
        }
    float rL[12];
    #pragma unroll
    for (int j = 0; j < 12; ++j) rL[j] = sLs[j];

    // --- per-thread statevector simulation, 2 elements (A,B) per thread ---
#define DECLP(n) v2 pA##n = { sPsi0[n].x, sPsi0[n].y }; v2 pB##n = pA##n;
    DECLP(0)  DECLP(1)  DECLP(2)  DECLP(3)
    DECLP(4)  DECLP(5)  DECLP(6)  DECLP(7)
    DECLP(8)  DECLP(9)  DECLP(10) DECLP(11)
    DECLP(12) DECLP(13) DECLP(14) DECLP(15)
#undef DECLP

    // new0 = aM*q0 + bM*q1 ;  new1 = -conj(bM)*q0 + conj(aM)*q1
    // complex mul packed:  aM*q = aMr*q + aMi*rot(q),  rot(q) = (-q.y, q.x)
#define BF(E,n0,n1) { \
    const v2 q0 = p##E##n0, q1 = p##E##n1; \
    const v2 r0 = { -q0.y, q0.x }; \
    const v2 r1 = { -q1.y, q1.x }; \
    v2 t0 = bMi2 * r1; \
    t0 = pkfma(bMr2, q1, t0); \
    t0 = pkfma(aMi2, r0, t0); \
    t0 = pkfma(aMr2, q0, t0); \
    v2 t1 = bMi2 * r0; \
    t1 = pkfma(bMr2, -q0, t1); \
    t1 = pkfma(aMi2, -r1, t1); \
    t1 = pkfma(aMr2, q1, t1); \
    p##E##n0 = t0; p##E##n1 = t1; \
}

    // Fused gate M = A^(kk) * RZ(z)*RY(a)*RX(a), element E, literal indices
#define GATE(E,kk,qq,zq,...) { \
    const float c_ = ch##E##qq, s_ = sh##E##qq; \
    const float cz_ = ch##E##zq, sz_ = sh##E##zq; \
    const float cc_ = c_*c_, ss_ = s_*s_, cs_ = c_*s_; \
    const float aVr = cc_*cz_ + ss_*sz_, aVi = ss_*cz_ - cc_*sz_; \
    const float bVr = -cs_*(cz_+sz_),  bVi = -cs_*(cz_-sz_); \
    const float2 fa = rA[kk][qq][0], fb = rA[kk][qq][1]; \
    const float aMr = fa.x*aVr - fa.y*aVi - (fb.x*bVr + fb.y*bVi); \
    const float aMi = fa.x*aVi + fa.y*aVr - (fb.y*bVr - fb.x*bVi); \
    const float bMr = fa.x*bVr - fa.y*bVi + (fb.x*aVr + fb.y*aVi); \
    const float bMi = fa.x*bVi + fa.y*bVr + (fb.y*aVr - fb.x*aVi); \
    const v2 aMr2 = { aMr, aMr }, aMi2 = { aMi, aMi }; \
    const v2 bMr2 = { bMr, bMr }, bMi2 = { bMi, bMi }; \
    __VA_ARGS__ \
}

    // CZ sign flips: negative diagonal on states {3,6,9,12}
#define CZFLIP(E) \
    p##E##3 = -p##E##3;  p##E##6 = -p##E##6; \
    p##E##9 = -p##E##9;  p##E##12 = -p##E##12;

#define LAYER(kk, DO_CZ) { \
    float chA0, shA0, chA1, shA1, chA2, shA2, chA3, shA3; \
    float chB0, shB0, chB1, shB1, chB2, shB2, chB3, shB3; \
    __sincosf(0.5f * rL[kk*4+0] * xrA.x, &shA0, &chA0); \
    __sincosf(0.5f * rL[kk*4+1] * xrA.y, &shA1, &chA1); \
    __sincosf(0.5f * rL[kk*4+2] * xrA.z, &shA2, &chA2); \
    __sincosf(0.5f * rL[kk*4+3] * xrA.w, &shA3, &chA3); \
    __sincosf(0.5f * rL[kk*4+0] * xrB.x, &shB0, &chB0); \
    __sincosf(0.5f * rL[kk*4+1] * xrB.y, &shB1, &chB1); \
    __sincosf(0.5f * rL[kk*4+2] * xrB.z, &shB2, &chB2); \
    __sincosf(0.5f * rL[kk*4+3] * xrB.w, &shB3, &chB3); \
    GATE(A,kk,0,0, BF(A,0,8)  BF(A,1,9)  BF(A,2,10) BF(A,3,11) BF(A,4,12) BF(A,5,13) BF(A,6,14)  BF(A,7,15))  \
    GATE(B,kk,0,0, BF(B,0,8)  BF(B,1,9)  BF(B,2,10) BF(B,3,11) BF(B,4,12) BF(B,5,13) BF(B,6,14)  BF(B,7,15))  \
    GATE(A,kk,1,0, BF(A,0,4)  BF(A,1,5)  BF(A,2,6)  BF(A,3,7)  BF(A,8,12) BF(A,9,13) BF(A,10,14) BF(A,11,15)) \
    GATE(B,kk,1,0, BF(B,0,4)  BF(B,1,5)  BF(B,2,6)  BF(B,3,7)  BF(B,8,12) BF(B,9,13) BF(B,10,14) BF(B,11,15)) \
    GATE(A,kk,2,1, BF(A,0,2)  BF(A,1,3)  BF(A,4,6)  BF(A,5,7)  BF(A,8,10) BF(A,9,11) BF(A,12,14) BF(A,13,15)) \
    GATE(B,kk,2,1, BF(B,0,2)  BF(B,1,3)  BF(B,4,6)  BF(B,5,7)  BF(B,8,10) BF(B,9,11) BF(B,12,14) BF(B,13,15)) \
    GATE(A,kk,3,1, BF(A,0,1)  BF(A,2,3)  BF(A,4,5)  BF(A,6,7)  BF(A,8,9)  BF(A,10,11) BF(A,12,13) BF(A,14,15))\
    GATE(B,kk,3,1, BF(B,0,1)  BF(B,2,3)  BF(B,4,5)  BF(B,6,7)  BF(B,8,9)  BF(B,10,11) BF(B,12,13) BF(B,14,15))\
    if (DO_CZ) { CZFLIP(A) CZFLIP(B) } \
}

    LAYER(0, 1)
    LAYER(1, 1)
    LAYER(2, 0)

#undef LAYER
#undef GATE
#undef BF
#undef CZFLIP

    // probs and Z expectations (qubit j reads bit (3-j)).
    // NOTE: indices must pass through a macro PARAMETER (PRB) — a literal
    // `p##E##0.x` is il-formed because `0.x` lexes as one pp-number token.
#define PRB(E,n) const float m##n = p##E##n.x*p##E##n.x + p##E##n.y*p##E##n.y;
#define EPILOGUE(E, idx) { \
    PRB(E,0)  PRB(E,1)  PRB(E,2)  PRB(E,3)  \
    PRB(E,4)  PRB(E,5)  PRB(E,6)  PRB(E,7)  \
    PRB(E,8)  PRB(E,9)  PRB(E,10) PRB(E,11) \
    PRB(E,12) PRB(E,13) PRB(E,14) PRB(E,15) \
    const float o0 = ((m0+m1)+(m2+m3)+(m4+m5)+(m6+m7)) \
                   - ((m8+m9)+(m10+m11)+(m12+m13)+(m14+m15)); \
    const float o1 = ((m0+m1)+(m2+m3)+(m8+m9)+(m10+m11)) \
                   - ((m4+m5)+(m6+m7)+(m12+m13)+(m14+m15)); \
    const float o2 = ((m0+m1)+(m4+m5)+(m8+m9)+(m12+m13)) \
                   - ((m2+m3)+(m6+m7)+(m10+m11)+(m14+m15)); \
    const float o3 = ((m0+m2)+(m4+m6)+(m8+m10)+(m12+m14)) \
                   - ((m1+m3)+(m5+m7)+(m9+m11)+(m13+m15)); \
    ((float4*)out)[idx] = make_float4(o0, o1, o2, o3); \
}

    EPILOGUE(A, i0)
    EPILOGUE(B, i1)
#undef EPILOGUE
#undef PRB
}

extern "C" void kernel_launch(void* const* d_in, const int* in_sizes, int n_in,
                              void* d_out, int out_size, void* d_ws, size_t ws_size,
                              hipStream_t stream) {
    const float* x     = (const float*)d_in[0];
    const float* theta = (const float*)d_in[1];
    const float* lmbd  = (const float*)d_in[2];
    float* out = (float*)d_out;
    vqc_kernel<<<dim3(GRID), dim3(BLOCK), 0, stream>>>(x, theta, lmbd, out);
}